// Round 5
// baseline (361.110 us; speedup 1.0000x reference)
//
#include <hip/hip_runtime.h>
#include <hip/hip_bf16.h>

#define HH 8
#define DD 64
#define NN 256
#define Q1c 21
#define Q2c 21
#define MM 4096
#define KTOT 2048   // HH*NN
#define BN 64

typedef __attribute__((ext_vector_type(8))) short short8;
typedef __attribute__((ext_vector_type(4))) float f32x4;
typedef __attribute__((ext_vector_type(16))) float f32x16;
typedef __attribute__((ext_vector_type(4))) unsigned int u32x4;

__device__ inline unsigned short f2bf(float f) {
  __hip_bfloat16 h = __float2bfloat16(f);
  return *reinterpret_cast<unsigned short*>(&h);
}

// Kernel 0: pack Z2 (int32 [j][m]) -> Z2t bytes [j/8][m][8] so k_gemm loads
// 8 indices with one dwordx2.
__global__ void k_pack(const int* __restrict__ Z2, unsigned char* __restrict__ Z2t) {
  int jb = blockIdx.x >> 4;                       // 0..31
  int m  = ((blockIdx.x & 15) << 8) + threadIdx.x;
  unsigned lo = 0, hi = 0;
#pragma unroll
  for (int r = 0; r < 4; ++r) lo |= ((unsigned)Z2[(jb*8 + r)*MM + m] & 255u) << (8*r);
#pragma unroll
  for (int r = 0; r < 4; ++r) hi |= ((unsigned)Z2[(jb*8 + 4 + r)*MM + m] & 255u) << (8*r);
  uint2 v; v.x = lo; v.y = hi;
  *reinterpret_cast<uint2*>(Z2t + ((size_t)jb*MM + m)*8) = v;
}

// Kernel 1: e = Q^T K per head, softmax over j. Writes sf (f32 [h][i][j]) and
// sfF: bf16 A-operand pre-fragmented as [ks=k/32][i][k%32].
__global__ void k_softmax(const float* __restrict__ Q, const float* __restrict__ K,
                          float* __restrict__ sf, unsigned short* __restrict__ sfF) {
  int h = blockIdx.x >> 8;
  int i = blockIdx.x & 255;
  int j = threadIdx.x;
  __shared__ float qs[DD];
  __shared__ float red[4];
  if (j < DD) qs[j] = Q[(h*DD + j)*NN + i];
  __syncthreads();
  float e = 0.f;
#pragma unroll
  for (int d = 0; d < DD; ++d) e = fmaf(qs[d], K[(h*DD + d)*NN + j], e);
  float mx = e;
#pragma unroll
  for (int o = 32; o; o >>= 1) mx = fmaxf(mx, __shfl_xor(mx, o));
  if ((j & 63) == 0) red[j >> 6] = mx;
  __syncthreads();
  mx = fmaxf(fmaxf(red[0], red[1]), fmaxf(red[2], red[3]));
  float p = __expf(e - mx);
  float s = p;
#pragma unroll
  for (int o = 32; o; o >>= 1) s += __shfl_xor(s, o);
  __syncthreads();
  if ((j & 63) == 0) red[j >> 6] = s;
  __syncthreads();
  s = red[0] + red[1] + red[2] + red[3];
  p = p / s;
  sf[(h*NN + i)*NN + j] = p;
  int ks = h*8 + (j >> 5);
  sfF[((ks*NN + i) << 5) + (j & 31)] = f2bf(p);
}

// Kernel 2: Mmat[h,k] upper-tri 36 entries via atomics.
__global__ void k_mmat(const float* __restrict__ sf, float* __restrict__ Mmat) {
  int i = blockIdx.x, j = threadIdx.x;
  float v[HH];
#pragma unroll
  for (int h = 0; h < HH; ++h) v[h] = sf[(h*NN + i)*NN + j];
  float pr[36];
  {
    int idx = 0;
#pragma unroll
    for (int h = 0; h < HH; ++h)
#pragma unroll
      for (int k = h; k < HH; ++k) pr[idx++] = v[h]*v[k];
  }
#pragma unroll
  for (int x = 0; x < 36; ++x) {
#pragma unroll
    for (int o = 32; o; o >>= 1) pr[x] += __shfl_xor(pr[x], o);
  }
  __shared__ float mm[4][36];
  int w = j >> 6;
  if ((j & 63) == 0) {
#pragma unroll
    for (int x = 0; x < 36; ++x) mm[w][x] = pr[x];
  }
  __syncthreads();
  if (j < 36) atomicAdd(&Mmat[j], mm[0][j] + mm[1][j] + mm[2][j] + mm[3][j]);
}

// Kernel 3: big GEMM, barrier-free + software-pipelined + XCD-swizzled.
// 2 waves x (128 rows x 64 cols), MFMA 32x32x16. Unit = 16 j x 2 heads = 32 k.
// Per unit u: issue z[u+2], A[u+1], bperm-gather B[u+1], 16 MFMA on (A,B)[u].
// V rows preloaded into 4 packed regs (heads 2hp/2hp+1 share Z2 indices).
__global__ __launch_bounds__(128, 2) void k_gemm(
    const unsigned short* __restrict__ sfF, const float* __restrict__ Vf,
    const int* __restrict__ Z1, const unsigned char* __restrict__ Z2t,
    float* __restrict__ Sexp, float* __restrict__ Ene) {
  const int t  = threadIdx.x;
  const int w  = t >> 6;          // 0..1
  const int l  = t & 63;
  const int lc = l & 31;          // col (B/C) / row (A) lane index
  const int lo = l >> 5;          // k-octet selector

  // XCD swizzle: xcd = bid%8 owns mblks [xcd*8, xcd*8+8) for all 21 a's;
  // within an XCD, a varies fastest (consecutive blocks share the Z1/Z2t slice).
  const int bid  = blockIdx.x;
  const int xcd  = bid & 7;
  const int q    = bid >> 3;        // 0..167
  const int mblk = xcd*8 + q/21;    // 0..63
  const int a_blk = q - (q/21)*21;  // 0..20
  const int m0 = mblk * 64;
  const int wrow = w * 128;

  f32x16 acc[4][2];               // [mr][ct]
#pragma unroll
  for (int mr = 0; mr < 4; ++mr)
#pragma unroll
    for (int ct = 0; ct < 2; ++ct)
#pragma unroll
      for (int r = 0; r < 16; ++r) acc[mr][ct][r] = 0.f;

  // V pairs for all 4 head pairs: lane c<21 holds (V[2hp+1][a][c]<<16)|V[2hp][a][c]
  int vpack[4];
#pragma unroll
  for (int hp = 0; hp < 4; ++hp) {
    float va = (l < Q1c) ? Vf[(2*hp    )*(Q1c*Q2c) + a_blk*Q2c + l] : 0.f;
    float vb = (l < Q1c) ? Vf[(2*hp + 1)*(Q1c*Q2c) + a_blk*Q2c + l] : 0.f;
    vpack[hp] = (int)(((unsigned)f2bf(vb) << 16) | (unsigned)f2bf(va));
  }

  const unsigned char*  zrow  = Z2t + ((size_t)(m0 + lc)) * 8;
  const unsigned short* abase = sfF + (((size_t)(wrow + lc)) << 5) + lo*8;

  // rotation buffers (all indices compile-time under full unroll)
  uint2  zr[3][2];        // [u%3][ct]  z bytes: jb = (u&15)*2 + lo
  short8 Ar[2][2][4];     // [u%2][th][mr]
  u32x4  Br[2][2][2];     // [u%2][ct][head]

#define ZLOAD(uu, slot)                                                        \
  {                                                                            \
    const int uc = ((uu) > 63) ? 63 : (uu);                                    \
    const int jb = ((uc) & 15)*2 + lo;                                         \
    _Pragma("unroll")                                                          \
    for (int ct = 0; ct < 2; ++ct)                                             \
      zr[slot][ct] = *reinterpret_cast<const uint2*>(                          \
          zrow + ((size_t)jb*MM + ct*32) * 8);                                 \
  }

#define ALOAD(uu, slot)                                                        \
  {                                                                            \
    const int uc = ((uu) > 63) ? 63 : (uu);                                    \
    _Pragma("unroll")                                                          \
    for (int th = 0; th < 2; ++th) {                                           \
      const int ks32 = (2*(uc >> 4) + th)*8 + ((uc >> 1) & 7);                 \
      const unsigned short* ab = abase + (((size_t)ks32 * NN) << 5)            \
                                 + (uc & 1)*16;                                \
      _Pragma("unroll")                                                        \
      for (int mr = 0; mr < 4; ++mr)                                           \
        Ar[slot][th][mr] = *reinterpret_cast<const short8*>(ab + mr*32*32);    \
    }                                                                          \
  }

#define GATHER(uu, slot)                                                       \
  {                                                                            \
    const int uc = ((uu) > 63) ? 63 : (uu);                                    \
    const int vp = vpack[uc >> 4];                                             \
    _Pragma("unroll")                                                          \
    for (int ct = 0; ct < 2; ++ct) {                                           \
      unsigned zlo = zr[(uc) % 3][ct].x, zhi = zr[(uc) % 3][ct].y;             \
      unsigned g[8];                                                           \
      _Pragma("unroll")                                                        \
      for (int r = 0; r < 8; ++r) {                                            \
        int c = (int)((r < 4 ? (zlo >> (8*r)) : (zhi >> (8*(r-4)))) & 255u);   \
        g[r] = (unsigned)__builtin_amdgcn_ds_bpermute(c << 2, vp);             \
      }                                                                        \
      u32x4 b0, b1;                                                            \
      _Pragma("unroll")                                                        \
      for (int p = 0; p < 4; ++p) {                                            \
        b0[p] = __builtin_amdgcn_perm(g[2*p+1], g[2*p], 0x05040100u);          \
        b1[p] = __builtin_amdgcn_perm(g[2*p+1], g[2*p], 0x07060302u);          \
      }                                                                        \
      Br[slot][ct][0] = b0;                                                    \
      Br[slot][ct][1] = b1;                                                    \
    }                                                                          \
  }

  // ---- prologue: z[0],z[1]; A[0]; B[0] ----
  ZLOAD(0, 0);
  ZLOAD(1, 1);
  ALOAD(0, 0);
  GATHER(0, 0);

#pragma unroll
  for (int u = 0; u < 64; ++u) {
    ZLOAD(u + 2, (u + 2) % 3);
    ALOAD(u + 1, (u + 1) & 1);
    GATHER(u + 1, (u + 1) & 1);
    // ---- MFMA on unit u ----
#pragma unroll
    for (int ct = 0; ct < 2; ++ct) {
      short8 B0 = *reinterpret_cast<short8*>(&Br[u & 1][ct][0]);
      short8 B1 = *reinterpret_cast<short8*>(&Br[u & 1][ct][1]);
#pragma unroll
      for (int mr = 0; mr < 4; ++mr)
        acc[mr][ct] = __builtin_amdgcn_mfma_f32_32x32x16_bf16(Ar[u & 1][0][mr], B0, acc[mr][ct], 0, 0, 0);
#pragma unroll
      for (int mr = 0; mr < 4; ++mr)
        acc[mr][ct] = __builtin_amdgcn_mfma_f32_32x32x16_bf16(Ar[u & 1][1][mr], B1, acc[mr][ct], 0, 0, 0);
    }
  }
#undef ZLOAD
#undef ALOAD
#undef GATHER

  // ---- fused epilogue ----
  // C/D 32x32: col = lane&31, row = (r&3) + 8*(r>>2) + 4*(lane>>5)
#pragma unroll
  for (int ct = 0; ct < 2; ++ct) {
    const int m = m0 + ct*32 + lc;
    float se = 0.f, en = 0.f;
#pragma unroll
    for (int mr = 0; mr < 4; ++mr) {
#pragma unroll
      for (int r = 0; r < 16; ++r) {
        int row = wrow + mr*32 + (r & 3) + 8*(r >> 2) + 4*lo;
        float g = acc[mr][ct][r];
        se += __expf(g);
        en += (Z1[row*MM + m] == a_blk) ? g : 0.f;
      }
    }
    se += __shfl_xor(se, 32);
    en += __shfl_xor(en, 32);
    if (lo == 0) {
      atomicAdd(&Sexp[m], se);
      atomicAdd(&Ene[m], en);
    }
  }
}

// Kernel 4: pl = -sum_m w[m]*(Ene[m] - log(Sexp[m] + 235)); block 16 adds reg term.
__global__ void k_final(const float* __restrict__ Sexp, const float* __restrict__ Ene,
                        const float* __restrict__ wts, const float* __restrict__ Mmat,
                        const float* __restrict__ Vf, float* __restrict__ out) {
  __shared__ float r4[4];
  float val = 0.f;
  if (blockIdx.x < 16) {
    int m = blockIdx.x * 256 + threadIdx.x;
    val = -wts[m] * (Ene[m] - logf(Sexp[m] + 235.0f));
  } else {
    int t = threadIdx.x;
    if (t < 64) {
      int h = t >> 3, k = t & 7;
      float dot = 0.f;
      for (int x = 0; x < Q1c*Q2c; ++x) dot += Vf[h*(Q1c*Q2c)+x] * Vf[k*(Q1c*Q2c)+x];
      int hh = (h < k) ? h : k;
      int kk = (h < k) ? k : h;
      int idx = hh*8 - (hh*(hh-1))/2 + (kk - hh);   // upper-tri index
      val = 0.001f * Mmat[idx] * dot;               // LAMBD = 0.001
    }
  }
#pragma unroll
  for (int o = 32; o; o >>= 1) val += __shfl_xor(val, o);
  int w = threadIdx.x >> 6;
  if ((threadIdx.x & 63) == 0) r4[w] = val;
  __syncthreads();
  if (threadIdx.x == 0) atomicAdd(out, r4[0] + r4[1] + r4[2] + r4[3]);
}

extern "C" void kernel_launch(void* const* d_in, const int* in_sizes, int n_in,
                              void* d_out, int out_size, void* d_ws, size_t ws_size,
                              hipStream_t stream) {
  const float* Q   = (const float*)d_in[0];
  const float* K   = (const float*)d_in[1];
  const float* V   = (const float*)d_in[2];
  const int*   Z1  = (const int*)d_in[3];
  const int*   Z2  = (const int*)d_in[4];
  const float* wts = (const float*)d_in[5];
  float* out = (float*)d_out;

  char* ws = (char*)d_ws;
  float*          sf   = (float*)ws;                               // 2 MB
  unsigned short* sfF  = (unsigned short*)(ws + (2u << 20));       // 1 MB
  unsigned char*  Z2t  = (unsigned char*)(ws + (3u << 20));        // 1 MB
  float*          Sexp = (float*)(ws + (4u << 20));                // 16 KB
  float*          Ene  = (float*)(ws + (4u << 20) + (16u << 10));  // 16 KB
  float*          Mmat = (float*)(ws + (4u << 20) + (32u << 10));  // 36 floats

  hipMemsetAsync(out, 0, sizeof(float), stream);
  hipMemsetAsync(ws + (4u << 20), 0, (32u << 10) + 256, stream);

  k_pack   <<<dim3(512),  dim3(256), 0, stream>>>(Z2, Z2t);
  k_softmax<<<dim3(2048), dim3(256), 0, stream>>>(Q, K, sf, sfF);
  k_mmat   <<<dim3(256),  dim3(256), 0, stream>>>(sf, Mmat);
  k_gemm   <<<dim3(1344), dim3(128), 0, stream>>>(sfF, V, Z1, Z2t, Sexp, Ene);
  k_final  <<<dim3(17),   dim3(256), 0, stream>>>(Sexp, Ene, wts, Mmat, V, out);
}

// Round 6
// 165.217 us; speedup vs baseline: 2.1857x; 2.1857x over previous
//
#include <hip/hip_runtime.h>
#include <hip/hip_bf16.h>

#define HH 8
#define DD 64
#define NN 256
#define Q1c 21
#define Q2c 21
#define MM 4096
#define KTOT 2048   // HH*NN
#define BN 64

typedef __attribute__((ext_vector_type(8))) short short8;
typedef __attribute__((ext_vector_type(4))) float f32x4;
typedef __attribute__((ext_vector_type(16))) float f32x16;
typedef __attribute__((ext_vector_type(4))) unsigned int u32x4;

__device__ inline unsigned short f2bf(float f) {
  __hip_bfloat16 h = __float2bfloat16(f);
  return *reinterpret_cast<unsigned short*>(&h);
}

// Kernel 0: pack Z2 (int32 [j][m]) -> Z2t bytes [j/8][m][8] so k_gemm loads
// 8 indices with one dwordx2.
__global__ void k_pack(const int* __restrict__ Z2, unsigned char* __restrict__ Z2t) {
  int jb = blockIdx.x >> 4;                       // 0..31
  int m  = ((blockIdx.x & 15) << 8) + threadIdx.x;
  unsigned lo = 0, hi = 0;
#pragma unroll
  for (int r = 0; r < 4; ++r) lo |= ((unsigned)Z2[(jb*8 + r)*MM + m] & 255u) << (8*r);
#pragma unroll
  for (int r = 0; r < 4; ++r) hi |= ((unsigned)Z2[(jb*8 + 4 + r)*MM + m] & 255u) << (8*r);
  uint2 v; v.x = lo; v.y = hi;
  *reinterpret_cast<uint2*>(Z2t + ((size_t)jb*MM + m)*8) = v;
}

// Kernel 1: e = Q^T K per head, softmax over j. Writes sf (f32 [h][i][j]) and
// sfF: bf16 A-operand pre-fragmented as [ks=k/32][i][k%32].
__global__ void k_softmax(const float* __restrict__ Q, const float* __restrict__ K,
                          float* __restrict__ sf, unsigned short* __restrict__ sfF) {
  int h = blockIdx.x >> 8;
  int i = blockIdx.x & 255;
  int j = threadIdx.x;
  __shared__ float qs[DD];
  __shared__ float red[4];
  if (j < DD) qs[j] = Q[(h*DD + j)*NN + i];
  __syncthreads();
  float e = 0.f;
#pragma unroll
  for (int d = 0; d < DD; ++d) e = fmaf(qs[d], K[(h*DD + d)*NN + j], e);
  float mx = e;
#pragma unroll
  for (int o = 32; o; o >>= 1) mx = fmaxf(mx, __shfl_xor(mx, o));
  if ((j & 63) == 0) red[j >> 6] = mx;
  __syncthreads();
  mx = fmaxf(fmaxf(red[0], red[1]), fmaxf(red[2], red[3]));
  float p = __expf(e - mx);
  float s = p;
#pragma unroll
  for (int o = 32; o; o >>= 1) s += __shfl_xor(s, o);
  __syncthreads();
  if ((j & 63) == 0) red[j >> 6] = s;
  __syncthreads();
  s = red[0] + red[1] + red[2] + red[3];
  p = p / s;
  sf[(h*NN + i)*NN + j] = p;
  int ks = h*8 + (j >> 5);
  sfF[((ks*NN + i) << 5) + (j & 31)] = f2bf(p);
}

// Kernel 2: Mmat[h,k] upper-tri 36 entries via atomics.
__global__ void k_mmat(const float* __restrict__ sf, float* __restrict__ Mmat) {
  int i = blockIdx.x, j = threadIdx.x;
  float v[HH];
#pragma unroll
  for (int h = 0; h < HH; ++h) v[h] = sf[(h*NN + i)*NN + j];
  float pr[36];
  {
    int idx = 0;
#pragma unroll
    for (int h = 0; h < HH; ++h)
#pragma unroll
      for (int k = h; k < HH; ++k) pr[idx++] = v[h]*v[k];
  }
#pragma unroll
  for (int x = 0; x < 36; ++x) {
#pragma unroll
    for (int o = 32; o; o >>= 1) pr[x] += __shfl_xor(pr[x], o);
  }
  __shared__ float mm[4][36];
  int w = j >> 6;
  if ((j & 63) == 0) {
#pragma unroll
    for (int x = 0; x < 36; ++x) mm[w][x] = pr[x];
  }
  __syncthreads();
  if (j < 36) atomicAdd(&Mmat[j], mm[0][j] + mm[1][j] + mm[2][j] + mm[3][j]);
}

// Kernel 3: big GEMM, barrier-free, spill-proof shape. 4 waves x (64 rows x
// 64 cols), MFMA 32x32x16. Each wave gathers its own B frags via ds_bpermute
// from V-row pairs in lane registers (heads 2hp/2hp+1 packed lo/hi, shared Z2
// indices). A streams from global sfF (L2-hot). Loop js outer (one z-load
// serves 4 head-pairs), hp inner as 4 explicit phases with alternating
// cur/nxt buffers (no rotation copies, no runtime indices).
__global__ __launch_bounds__(256, 3) void k_gemm(
    const unsigned short* __restrict__ sfF, const float* __restrict__ Vf,
    const int* __restrict__ Z1, const unsigned char* __restrict__ Z2t,
    float* __restrict__ Sexp, float* __restrict__ Ene) {
  const int t  = threadIdx.x;
  const int w  = t >> 6;          // 0..3 row-group
  const int l  = t & 63;
  const int lc = l & 31;          // col (B/C) / row (A) lane index
  const int lo = l >> 5;          // k-octet selector

  // XCD swizzle: xcd = bid%8 owns mblks [xcd*8, xcd*8+8) for all 21 a's.
  const int bid  = blockIdx.x;
  const int xcd  = bid & 7;
  const int q    = bid >> 3;        // 0..167
  const int mblk = xcd*8 + q/21;    // 0..63
  const int a_blk = q - (q/21)*21;  // 0..20
  const int m0 = mblk * 64;
  const int wrow = w * 64;

  f32x16 acc[2][2];               // [mr][ct]
#pragma unroll
  for (int mr = 0; mr < 2; ++mr)
#pragma unroll
    for (int ct = 0; ct < 2; ++ct)
#pragma unroll
      for (int r = 0; r < 16; ++r) acc[mr][ct][r] = 0.f;

  // V pairs for all 4 head pairs: lane c<21 holds (V[2hp+1][a][c]<<16)|V[2hp][a][c]
  int vpack[4];
#pragma unroll
  for (int hp = 0; hp < 4; ++hp) {
    float va = (l < Q1c) ? Vf[(2*hp    )*(Q1c*Q2c) + a_blk*Q2c + l] : 0.f;
    float vb = (l < Q1c) ? Vf[(2*hp + 1)*(Q1c*Q2c) + a_blk*Q2c + l] : 0.f;
    vpack[hp] = (int)(((unsigned)f2bf(vb) << 16) | (unsigned)f2bf(va));
  }

  const unsigned char*  zrow  = Z2t + ((size_t)(m0 + lc)) * 8;
  const unsigned short* abase = sfF + (((size_t)(wrow + lc)) << 5) + lo*8;

  uint2  zc[2], zn[2];            // [ct]
  short8 Ac[2][2], An[2][2];      // [th][mr]
  short8 Bc[2][2], Bn[2][2];      // [ct][th]

  // unit(js,hp): k-step of 16 (j in [js*16,js*16+16)) for heads 2hp,2hp+1.
#define ZLOAD(jss, zd)                                                         \
  {                                                                            \
    const int jb = (jss)*2 + lo;                                               \
    _Pragma("unroll")                                                          \
    for (int ct = 0; ct < 2; ++ct)                                             \
      zd[ct] = *reinterpret_cast<const uint2*>(                                \
          zrow + ((size_t)jb*MM + ct*32) * 8);                                 \
  }

#define ALOAD(jss, hpp, Ad)                                                    \
  {                                                                            \
    _Pragma("unroll")                                                          \
    for (int th = 0; th < 2; ++th) {                                           \
      const int ks32 = (2*(hpp) + th)*8 + ((jss) >> 1);                        \
      const unsigned short* ab = abase + (((size_t)ks32 * NN) << 5)            \
                                 + ((jss) & 1)*16;                             \
      _Pragma("unroll")                                                        \
      for (int mr = 0; mr < 2; ++mr)                                           \
        Ad[th][mr] = *reinterpret_cast<const short8*>(ab + mr*32*32);          \
    }                                                                          \
  }

#define GATHER(zs, hpp, Bd)                                                    \
  {                                                                            \
    const int vp = vpack[hpp];                                                 \
    _Pragma("unroll")                                                          \
    for (int ct = 0; ct < 2; ++ct) {                                           \
      unsigned zlo = zs[ct].x, zhi = zs[ct].y;                                 \
      unsigned g[8];                                                           \
      _Pragma("unroll")                                                        \
      for (int r = 0; r < 8; ++r) {                                            \
        int c = (int)((r < 4 ? (zlo >> (8*r)) : (zhi >> (8*(r-4)))) & 255u);   \
        g[r] = (unsigned)__builtin_amdgcn_ds_bpermute(c << 2, vp);             \
      }                                                                        \
      unsigned b0[4], b1[4];                                                   \
      _Pragma("unroll")                                                        \
      for (int p = 0; p < 4; ++p) {                                            \
        b0[p] = __builtin_amdgcn_perm(g[2*p+1], g[2*p], 0x05040100u);          \
        b1[p] = __builtin_amdgcn_perm(g[2*p+1], g[2*p], 0x07060302u);          \
      }                                                                        \
      Bd[ct][0] = *reinterpret_cast<short8*>(b0);                              \
      Bd[ct][1] = *reinterpret_cast<short8*>(b1);                              \
    }                                                                          \
  }

#define MFMA8(Au, Bu)                                                          \
  {                                                                            \
    _Pragma("unroll")                                                          \
    for (int th = 0; th < 2; ++th)                                             \
      _Pragma("unroll")                                                        \
      for (int mr = 0; mr < 2; ++mr)                                           \
        _Pragma("unroll")                                                      \
        for (int ct = 0; ct < 2; ++ct)                                         \
          acc[mr][ct] = __builtin_amdgcn_mfma_f32_32x32x16_bf16(               \
              Au[th][mr], Bu[ct][th], acc[mr][ct], 0, 0, 0);                   \
  }

  // ---- prologue ----
  ZLOAD(0, zc);
  ALOAD(0, 0, Ac);
  GATHER(zc, 0, Bc);

  for (int js = 0; js < 16; ++js) {
    const int jsn = (js < 15) ? js + 1 : 15;
    ZLOAD(jsn, zn);
    // phase 0: cur=(js,0) in Ac/Bc; prefetch (js,1) -> An/Bn
    ALOAD(js, 1, An);  GATHER(zc, 1, Bn);  MFMA8(Ac, Bc);
    // phase 1: cur=(js,1); prefetch (js,2) -> Ac/Bc
    ALOAD(js, 2, Ac);  GATHER(zc, 2, Bc);  MFMA8(An, Bn);
    // phase 2: cur=(js,2); prefetch (js,3) -> An/Bn
    ALOAD(js, 3, An);  GATHER(zc, 3, Bn);  MFMA8(Ac, Bc);
    // phase 3: cur=(js,3); prefetch (js+1,0) -> Ac/Bc (uses zn)
    ALOAD(jsn, 0, Ac); GATHER(zn, 0, Bc);  MFMA8(An, Bn);
    zc[0] = zn[0]; zc[1] = zn[1];
  }
#undef ZLOAD
#undef ALOAD
#undef GATHER
#undef MFMA8

  // ---- fused epilogue ----
  // C/D 32x32: col = lane&31, row = (r&3) + 8*(r>>2) + 4*(lane>>5)
#pragma unroll
  for (int ct = 0; ct < 2; ++ct) {
    const int m = m0 + ct*32 + lc;
    float se = 0.f, en = 0.f;
#pragma unroll
    for (int mr = 0; mr < 2; ++mr) {
#pragma unroll
      for (int r = 0; r < 16; ++r) {
        int row = wrow + mr*32 + (r & 3) + 8*(r >> 2) + 4*lo;
        float g = acc[mr][ct][r];
        se += __expf(g);
        en += (Z1[row*MM + m] == a_blk) ? g : 0.f;
      }
    }
    se += __shfl_xor(se, 32);
    en += __shfl_xor(en, 32);
    if (lo == 0) {
      atomicAdd(&Sexp[m], se);
      atomicAdd(&Ene[m], en);
    }
  }
}

// Kernel 4: pl = -sum_m w[m]*(Ene[m] - log(Sexp[m] + 235)); block 16 adds reg term.
__global__ void k_final(const float* __restrict__ Sexp, const float* __restrict__ Ene,
                        const float* __restrict__ wts, const float* __restrict__ Mmat,
                        const float* __restrict__ Vf, float* __restrict__ out) {
  __shared__ float r4[4];
  float val = 0.f;
  if (blockIdx.x < 16) {
    int m = blockIdx.x * 256 + threadIdx.x;
    val = -wts[m] * (Ene[m] - logf(Sexp[m] + 235.0f));
  } else {
    int t = threadIdx.x;
    if (t < 64) {
      int h = t >> 3, k = t & 7;
      float dot = 0.f;
      for (int x = 0; x < Q1c*Q2c; ++x) dot += Vf[h*(Q1c*Q2c)+x] * Vf[k*(Q1c*Q2c)+x];
      int hh = (h < k) ? h : k;
      int kk = (h < k) ? k : h;
      int idx = hh*8 - (hh*(hh-1))/2 + (kk - hh);   // upper-tri index
      val = 0.001f * Mmat[idx] * dot;               // LAMBD = 0.001
    }
  }
#pragma unroll
  for (int o = 32; o; o >>= 1) val += __shfl_xor(val, o);
  int w = threadIdx.x >> 6;
  if ((threadIdx.x & 63) == 0) r4[w] = val;
  __syncthreads();
  if (threadIdx.x == 0) atomicAdd(out, r4[0] + r4[1] + r4[2] + r4[3]);
}

extern "C" void kernel_launch(void* const* d_in, const int* in_sizes, int n_in,
                              void* d_out, int out_size, void* d_ws, size_t ws_size,
                              hipStream_t stream) {
  const float* Q   = (const float*)d_in[0];
  const float* K   = (const float*)d_in[1];
  const float* V   = (const float*)d_in[2];
  const int*   Z1  = (const int*)d_in[3];
  const int*   Z2  = (const int*)d_in[4];
  const float* wts = (const float*)d_in[5];
  float* out = (float*)d_out;

  char* ws = (char*)d_ws;
  float*          sf   = (float*)ws;                               // 2 MB
  unsigned short* sfF  = (unsigned short*)(ws + (2u << 20));       // 1 MB
  unsigned char*  Z2t  = (unsigned char*)(ws + (3u << 20));        // 1 MB
  float*          Sexp = (float*)(ws + (4u << 20));                // 16 KB
  float*          Ene  = (float*)(ws + (4u << 20) + (16u << 10));  // 16 KB
  float*          Mmat = (float*)(ws + (4u << 20) + (32u << 10));  // 36 floats

  hipMemsetAsync(out, 0, sizeof(float), stream);
  hipMemsetAsync(ws + (4u << 20), 0, (32u << 10) + 256, stream);

  k_pack   <<<dim3(512),  dim3(256), 0, stream>>>(Z2, Z2t);
  k_softmax<<<dim3(2048), dim3(256), 0, stream>>>(Q, K, sf, sfF);
  k_mmat   <<<dim3(256),  dim3(256), 0, stream>>>(sf, Mmat);
  k_gemm   <<<dim3(1344), dim3(256), 0, stream>>>(sfF, V, Z1, Z2t, Sexp, Ene);
  k_final  <<<dim3(17),   dim3(256), 0, stream>>>(Sexp, Ene, wts, Mmat, V, out);
}

// Round 7
// 141.085 us; speedup vs baseline: 2.5595x; 1.1710x over previous
//
#include <hip/hip_runtime.h>
#include <hip/hip_bf16.h>

#define HH 8
#define DD 64
#define NN 256
#define Q1c 21
#define Q2c 21
#define MM 4096
#define KTOT 2048   // HH*NN

typedef __attribute__((ext_vector_type(4))) int i32x4;
typedef __attribute__((ext_vector_type(16))) int i32x16;

// Kernel 0: pack Z2 (int32 [j][m]) -> Z2t bytes [j/8][m][8] so k_gemm loads
// 8 indices with one dwordx2.
__global__ void k_pack(const int* __restrict__ Z2, unsigned char* __restrict__ Z2t) {
  int jb = blockIdx.x >> 4;                       // 0..31
  int m  = ((blockIdx.x & 15) << 8) + threadIdx.x;
  unsigned lo = 0, hi = 0;
#pragma unroll
  for (int r = 0; r < 4; ++r) lo |= ((unsigned)Z2[(jb*8 + r)*MM + m] & 255u) << (8*r);
#pragma unroll
  for (int r = 0; r < 4; ++r) hi |= ((unsigned)Z2[(jb*8 + 4 + r)*MM + m] & 255u) << (8*r);
  uint2 v; v.x = lo; v.y = hi;
  *reinterpret_cast<uint2*>(Z2t + ((size_t)jb*MM + m)*8) = v;
}

// Kernel 0b: quantize V: sV = max|V|/127; qVt[(a*21+c)*8 + h] = round(V[h][a][c]/sV).
__global__ void k_prep(const float* __restrict__ Vf, unsigned char* __restrict__ qVt,
                       float* __restrict__ sVbuf) {
  __shared__ float red[4];
  int t = threadIdx.x;
  float mx = 0.f;
  for (int x = t; x < HH*Q1c*Q2c; x += 256) mx = fmaxf(mx, fabsf(Vf[x]));
#pragma unroll
  for (int o = 32; o; o >>= 1) mx = fmaxf(mx, __shfl_xor(mx, o));
  if ((t & 63) == 0) red[t >> 6] = mx;
  __syncthreads();
  mx = fmaxf(fmaxf(red[0], red[1]), fmaxf(red[2], red[3]));
  if (t == 0) sVbuf[0] = mx / 127.f;
  float inv = 127.f / mx;
  for (int x = t; x < HH*Q1c*Q2c; x += 256) {
    int h = x / (Q1c*Q2c);
    int rem = x - h*(Q1c*Q2c);
    int a = rem / Q2c, c = rem - a*Q2c;
    int qv = __float2int_rn(Vf[x] * inv);
    qVt[(a*Q2c + c)*8 + h] = (unsigned char)(qv & 255);
  }
}

// Kernel 1: e = Q^T K per head, softmax over j. Writes sf (f32, for k_mmat) and
// qsfF: u8 A-operand pre-fragmented for i8 MFMA with k-order pi(s,lo,d,b):
// j = u*16 + 8*lo + 2*s01(+hf*4) + (d>>1), h = (d&1)*4 + b.
__global__ void k_softmax(const float* __restrict__ Q, const float* __restrict__ K,
                          float* __restrict__ sf, unsigned char* __restrict__ qsfF) {
  int h = blockIdx.x >> 8;
  int i = blockIdx.x & 255;
  int j = threadIdx.x;
  __shared__ float qs[DD];
  __shared__ float red[4];
  if (j < DD) qs[j] = Q[(h*DD + j)*NN + i];
  __syncthreads();
  float e = 0.f;
#pragma unroll
  for (int d = 0; d < DD; ++d) e = fmaf(qs[d], K[(h*DD + d)*NN + j], e);
  float mx = e;
#pragma unroll
  for (int o = 32; o; o >>= 1) mx = fmaxf(mx, __shfl_xor(mx, o));
  if ((j & 63) == 0) red[j >> 6] = mx;
  __syncthreads();
  mx = fmaxf(fmaxf(red[0], red[1]), fmaxf(red[2], red[3]));
  float p = __expf(e - mx);
  float s = p;
#pragma unroll
  for (int o = 32; o; o >>= 1) s += __shfl_xor(s, o);
  __syncthreads();
  if ((j & 63) == 0) red[j >> 6] = s;
  __syncthreads();
  s = red[0] + red[1] + red[2] + red[3];
  p = p / s;
  sf[(h*NN + i)*NN + j] = p;
  // i8 fragment placement
  int u = j >> 4, r8 = j & 15;
  int lo = r8 >> 3, r = r8 & 7;
  int ss = r >> 1, dl = r & 1;
  int d = dl*2 + (h >> 2), b = h & 3;
  qsfF[(((size_t)(u*NN + i)) << 7) + ss*32 + lo*16 + d*4 + b] =
      (unsigned char)__float2int_rn(p * 127.f);
}

// Kernel 2: Mmat[h,k] upper-tri 36 entries via atomics.
__global__ void k_mmat(const float* __restrict__ sf, float* __restrict__ Mmat) {
  int i = blockIdx.x, j = threadIdx.x;
  float v[HH];
#pragma unroll
  for (int h = 0; h < HH; ++h) v[h] = sf[(h*NN + i)*NN + j];
  float pr[36];
  {
    int idx = 0;
#pragma unroll
    for (int h = 0; h < HH; ++h)
#pragma unroll
      for (int k = h; k < HH; ++k) pr[idx++] = v[h]*v[k];
  }
#pragma unroll
  for (int x = 0; x < 36; ++x) {
#pragma unroll
    for (int o = 32; o; o >>= 1) pr[x] += __shfl_xor(pr[x], o);
  }
  __shared__ float mm[4][36];
  int w = j >> 6;
  if ((j & 63) == 0) {
#pragma unroll
    for (int x = 0; x < 36; ++x) mm[w][x] = pr[x];
  }
  __syncthreads();
  if (j < 36) atomicAdd(&Mmat[j], mm[0][j] + mm[1][j] + mm[2][j] + mm[3][j]);
}

// Kernel 3: big GEMM in int8, barrier-free. 4 waves x (64 rows x 64 cols),
// MFMA i32_32x32x32_i8. One ds_bpermute gathers 4 heads (bytes of qVt dword);
// gathered dwords ARE the B-operand dwords (k-order pi chosen to match).
// Unit = 16 j x 8 h = 128 k; half-unit = 64 k; explicit dbuf phases (no spill).
__global__ __launch_bounds__(256, 3) void k_gemm(
    const unsigned char* __restrict__ qsfF, const unsigned char* __restrict__ qVt,
    const float* __restrict__ sVbuf,
    const int* __restrict__ Z1, const unsigned char* __restrict__ Z2t,
    float* __restrict__ Sexp, float* __restrict__ Ene) {
  const int t  = threadIdx.x;
  const int w  = t >> 6;          // 0..3 row-group
  const int l  = t & 63;
  const int lc = l & 31;          // col (B/C) / row (A) lane index
  const int lo = l >> 5;          // k-octet selector

  // XCD swizzle: xcd = bid%8 owns mblks [xcd*8, xcd*8+8) for all 21 a's.
  const int bid  = blockIdx.x;
  const int xcd  = bid & 7;
  const int q    = bid >> 3;        // 0..167
  const int mblk = xcd*8 + q/21;    // 0..63
  const int a_blk = q - (q/21)*21;  // 0..20
  const int m0 = mblk * 64;
  const int wrow = w * 64;

  i32x16 acc[2][2];               // [mr][ct]
#pragma unroll
  for (int mr = 0; mr < 2; ++mr)
#pragma unroll
    for (int ct = 0; ct < 2; ++ct)
#pragma unroll
      for (int r = 0; r < 16; ++r) acc[mr][ct][r] = 0;

  // gather tables: lane c<21 holds qV dwords for (a_blk, c): heads 0-3, 4-7
  const int lc21 = (lc < Q1c) ? lc : (Q1c - 1);
  const int tab0 = *reinterpret_cast<const int*>(qVt + (a_blk*Q2c + lc21)*8);
  const int tab1 = *reinterpret_cast<const int*>(qVt + (a_blk*Q2c + lc21)*8 + 4);

  const unsigned char* zrow = Z2t + ((size_t)(m0 + lc)) * 8;

  uint2 za[2], zb[2];             // [ct]
  int   ga[2][4][2], gb[2][4][2]; // [ct][r][hq]
  i32x4 Aa[2][2], Ab[2][2];       // [s01][mr]

#define ZLOADU(uu, zd)                                                         \
  {                                                                            \
    const int uc = ((uu) > 15) ? 15 : (uu);                                    \
    const int jb = uc*2 + lo;                                                  \
    zd[0] = *reinterpret_cast<const uint2*>(zrow + ((size_t)jb*MM)*8);         \
    zd[1] = *reinterpret_cast<const uint2*>(zrow + ((size_t)jb*MM + 32)*8);    \
  }

#define GATH(gd, zs, HF)                                                       \
  {                                                                            \
    _Pragma("unroll")                                                          \
    for (int ct = 0; ct < 2; ++ct) {                                           \
      const unsigned zz = (HF) ? zs[ct].y : zs[ct].x;                          \
      _Pragma("unroll")                                                        \
      for (int r = 0; r < 4; ++r) {                                            \
        const int c = (int)((zz >> (8*r)) & 255u) << 2;                        \
        gd[ct][r][0] = __builtin_amdgcn_ds_bpermute(c, tab0);                  \
        gd[ct][r][1] = __builtin_amdgcn_ds_bpermute(c, tab1);                  \
      }                                                                        \
    }                                                                          \
  }

#define ALOADU(uu, hf, Ad)                                                     \
  {                                                                            \
    const int uc = ((uu) > 15) ? 15 : (uu);                                    \
    const unsigned char* ab = qsfF + ((size_t)uc << 15)                        \
        + (size_t)(wrow + lc)*128 + (hf)*64 + lo*16;                           \
    _Pragma("unroll")                                                          \
    for (int s01 = 0; s01 < 2; ++s01)                                          \
      _Pragma("unroll")                                                        \
      for (int mr = 0; mr < 2; ++mr)                                           \
        Ad[s01][mr] = *reinterpret_cast<const i32x4*>(ab + s01*32 + mr*32*128);\
  }

#define MFMA8(Ad, gd)                                                          \
  {                                                                            \
    _Pragma("unroll")                                                          \
    for (int s01 = 0; s01 < 2; ++s01)                                          \
      _Pragma("unroll")                                                        \
      for (int ct = 0; ct < 2; ++ct) {                                         \
        i32x4 B = (i32x4){gd[ct][2*s01][0], gd[ct][2*s01][1],                  \
                          gd[ct][2*s01+1][0], gd[ct][2*s01+1][1]};             \
        _Pragma("unroll")                                                      \
        for (int mr = 0; mr < 2; ++mr)                                         \
          acc[mr][ct] = __builtin_amdgcn_mfma_i32_32x32x32_i8(                 \
              Ad[s01][mr], B, acc[mr][ct], 0, 0, 0);                           \
      }                                                                        \
  }

  // ---- prologue ----
  ZLOADU(0, za); ZLOADU(1, zb);
  GATH(ga, za, 0);
  ALOADU(0, 0, Aa);

  for (int u = 0; u < 16; u += 2) {
    GATH(gb, za, 1);  ALOADU(u,   1, Ab);  MFMA8(Aa, ga);
    ZLOADU(u+2, za);
    GATH(ga, zb, 0);  ALOADU(u+1, 0, Aa);  MFMA8(Ab, gb);
    GATH(gb, zb, 1);  ALOADU(u+1, 1, Ab);  MFMA8(Aa, ga);
    ZLOADU(u+3, zb);
    GATH(ga, za, 0);  ALOADU(u+2, 0, Aa);  MFMA8(Ab, gb);
  }
#undef ZLOADU
#undef GATH
#undef ALOADU
#undef MFMA8

  // ---- fused epilogue: dequant, exp-sum, Z1-selected sum per column m ----
  const float scale = sVbuf[0] * (1.f / 127.f);
#pragma unroll
  for (int ct = 0; ct < 2; ++ct) {
    const int m = m0 + ct*32 + lc;
    float se = 0.f, en = 0.f;
#pragma unroll
    for (int mr = 0; mr < 2; ++mr) {
#pragma unroll
      for (int r = 0; r < 16; ++r) {
        int row = wrow + mr*32 + (r & 3) + 8*(r >> 2) + 4*lo;
        float g = (float)acc[mr][ct][r] * scale;
        se += __expf(g);
        en += (Z1[row*MM + m] == a_blk) ? g : 0.f;
      }
    }
    se += __shfl_xor(se, 32);
    en += __shfl_xor(en, 32);
    if (lo == 0) {
      atomicAdd(&Sexp[m], se);
      atomicAdd(&Ene[m], en);
    }
  }
}

// Kernel 4: pl = -sum_m w[m]*(Ene[m] - log(Sexp[m] + 235)); block 16 adds reg term.
__global__ void k_final(const float* __restrict__ Sexp, const float* __restrict__ Ene,
                        const float* __restrict__ wts, const float* __restrict__ Mmat,
                        const float* __restrict__ Vf, float* __restrict__ out) {
  __shared__ float r4[4];
  float val = 0.f;
  if (blockIdx.x < 16) {
    int m = blockIdx.x * 256 + threadIdx.x;
    val = -wts[m] * (Ene[m] - logf(Sexp[m] + 235.0f));
  } else {
    int t = threadIdx.x;
    if (t < 64) {
      int h = t >> 3, k = t & 7;
      float dot = 0.f;
      for (int x = 0; x < Q1c*Q2c; ++x) dot += Vf[h*(Q1c*Q2c)+x] * Vf[k*(Q1c*Q2c)+x];
      int hh = (h < k) ? h : k;
      int kk = (h < k) ? k : h;
      int idx = hh*8 - (hh*(hh-1))/2 + (kk - hh);   // upper-tri index
      val = 0.001f * Mmat[idx] * dot;               // LAMBD = 0.001
    }
  }
#pragma unroll
  for (int o = 32; o; o >>= 1) val += __shfl_xor(val, o);
  int w = threadIdx.x >> 6;
  if ((threadIdx.x & 63) == 0) r4[w] = val;
  __syncthreads();
  if (threadIdx.x == 0) atomicAdd(out, r4[0] + r4[1] + r4[2] + r4[3]);
}

extern "C" void kernel_launch(void* const* d_in, const int* in_sizes, int n_in,
                              void* d_out, int out_size, void* d_ws, size_t ws_size,
                              hipStream_t stream) {
  const float* Q   = (const float*)d_in[0];
  const float* K   = (const float*)d_in[1];
  const float* V   = (const float*)d_in[2];
  const int*   Z1  = (const int*)d_in[3];
  const int*   Z2  = (const int*)d_in[4];
  const float* wts = (const float*)d_in[5];
  float* out = (float*)d_out;

  char* ws = (char*)d_ws;
  float*          sf   = (float*)ws;                               // 2 MB
  unsigned char*  qsfF = (unsigned char*)(ws + (2u << 20));        // 512 KB
  unsigned char*  Z2t  = (unsigned char*)(ws + (3u << 20));        // 1 MB
  float*          Sexp = (float*)(ws + (4u << 20));                // 16 KB
  float*          Ene  = (float*)(ws + (4u << 20) + (16u << 10));  // 16 KB
  float*          Mmat = (float*)(ws + (4u << 20) + (32u << 10));  // 144 B
  unsigned char*  qVt  = (unsigned char*)(ws + (4u << 20) + (40u << 10)); // 3528 B
  float*          sVbuf= (float*)(ws + (4u << 20) + (48u << 10));  // 4 B

  hipMemsetAsync(out, 0, sizeof(float), stream);
  hipMemsetAsync(ws + (4u << 20), 0, (33u << 10), stream);

  k_pack   <<<dim3(512),  dim3(256), 0, stream>>>(Z2, Z2t);
  k_prep   <<<dim3(1),    dim3(256), 0, stream>>>(V, qVt, sVbuf);
  k_softmax<<<dim3(2048), dim3(256), 0, stream>>>(Q, K, sf, qsfF);
  k_mmat   <<<dim3(256),  dim3(256), 0, stream>>>(sf, Mmat);
  k_gemm   <<<dim3(1344), dim3(256), 0, stream>>>(qsfF, qVt, sVbuf, Z1, Z2t, Sexp, Ene);
  k_final  <<<dim3(17),   dim3(256), 0, stream>>>(Sexp, Ene, wts, Mmat, V, out);
}